// Round 6
// baseline (121.568 us; speedup 1.0000x reference)
//
#include <hip/hip_runtime.h>
#include <stdint.h>

// ---------------------------------------------------------------------------
// B=2048, F0=40, D=32, LAYER0=LAYER1=128.  Rows r=b*32+d (65536).
//   phase0: h0[r,s] = relu(sum_{i<40,j<40} X[r,i]X[r,j] W0[i,j,s] + b0[s])
//   phase1: d1[r,s] = relu(sum_{i<40,j<64} X[r,i]NH[r,j] W1[i,j,s] + b1[s])
//   out[b,0:64] = sum_d h0[:,64:128]; out[b,64:192] = sum_d d1
//
// Round-15: 32x32x16 MFMA = bv-lean AND 64-arch-register-fit.
// Invariant from r11-r14: the compiler allocates ~64 arch VGPRs (arch/acc
// split); any datapath needing more spills (r14: WRITE 17.9MB at jv16+av16+
// xi20).  The 16x16-based bv-lean variant cannot fit 64.  Switching the
// MFMA shape to 32x32x16 restructures the registers: wave = 64 rows x 32
// cols via 2 row-tiles of 32; jv[2]=8 (was 16), av=4 transient (was 16),
// bv 2xb128/tile (bv-lean), acc 2xf32x16=32.  Arch ~55-60 <= 64.  Bonus:
// 32x32 pipe is 2495 vs 2075 TF -> MFMA floor 69K -> 57K cyc (24us).
// Structure: ONE 1024-thr block/CU (16 waves = 4 rt x 4 sq, 4 waves/SIMD by
// construction), PERIOD=3 global_load_lds double buffer, 1 barrier/period.
// W layout [sq][kh][lane][oct]: identity DMA staging + lane-linear
// conflict-free ds_read_b128 for the 32x32 B-fragment (col=lane&31,
// k=(lane>>5)*8+e within K16-half kh).  C/D layout (m74/m101): col=lane&31,
// row=(reg&3)+8*(reg>>2)+4*(lane>>5) -> epilogue d-sum = 16 adds +
// shfl_xor(32); bias is one scalar/lane.
// Carried: symmetrized-triangular W0 (30 tiles), phase1 pad tile 80 (zero
// W; jv reads zeroed NH cols 64..71), fp16 datapath, per-period barriers.
// ---------------------------------------------------------------------------

typedef __attribute__((ext_vector_type(8))) _Float16 half8;
typedef __attribute__((ext_vector_type(2))) _Float16 half2v;
typedef __attribute__((ext_vector_type(16))) float f32x16;

#define T0 30        // phase0 tiles after triangular drop
#define T1P 81       // phase1 tiles incl. 1 zero pad tile (80 real)
#define PERIOD 3
#define WBUF 12288   // halfwords per Wb buffer (3 tiles x 4096)

// phase-0 triangular schedule: jc blocks of sizes 2,4,6,8,10 (starts 0,2,6,12,20)
__host__ __device__ constexpr int ic0_of(int t) {
    return (t < 2) ? t : (t < 6) ? (t - 2) : (t < 12) ? (t - 6)
         : (t < 20) ? (t - 12) : (t - 20);
}
__host__ __device__ constexpr int jc0_of(int t) {
    return (t < 2) ? 0 : (t < 6) ? 1 : (t < 12) ? 2 : (t < 20) ? 3 : 4;
}

__device__ __forceinline__ unsigned short f2h(float f) {   // v_cvt_f16_f32, RNE
    return __builtin_bit_cast(unsigned short, (_Float16)f);
}
// async global->LDS DMA, 16 B/lane.  lds dest = (wave-uniform base) + lane*16.
__device__ __forceinline__ void gl_lds16(const unsigned short* g, unsigned short* l) {
    __builtin_amdgcn_global_load_lds(
        (const __attribute__((address_space(1))) unsigned int*)g,
        (__attribute__((address_space(3))) unsigned int*)l,
        16, 0, 0);
}
// A-fragment: broadcast x-scalar (both halves of xs) times 8 packed j-values.
__device__ __forceinline__ uint4 avmul(half2v xs, uint4 jv) {
    uint4 r;
    r.x = __builtin_bit_cast(unsigned int, (half2v)(xs * __builtin_bit_cast(half2v, jv.x)));
    r.y = __builtin_bit_cast(unsigned int, (half2v)(xs * __builtin_bit_cast(half2v, jv.y)));
    r.z = __builtin_bit_cast(unsigned int, (half2v)(xs * __builtin_bit_cast(half2v, jv.z)));
    r.w = __builtin_bit_cast(unsigned int, (half2v)(xs * __builtin_bit_cast(half2v, jv.w)));
    return r;
}

// ---------------------------------------------------------------------------
// Permute W -> Wp[t][ pos = sq*1024 + kh*512 + lane*8 + e ]:
//   s = sq*32 + (lane&31), hb = lane>>5, k = kh*16 + hb*8 + e,
//   i = ic*4 + kh*2 + hb, j = jc*8 + e.
// This is EXACTLY the 32x32x16 B-fragment read order (16B/lane, lane-linear)
// -> conflict-free ds_read_b128 AND identity global_load_lds staging.
// Phase0: symmetrized triangular Wsym.  Phase1 tile 80 = zeros (pad).
// 111 blocks x 256 threads, 16 halfwords each.
// ---------------------------------------------------------------------------
__global__ void permute_w_both(const float* __restrict__ W0, const float* __restrict__ W1,
                               unsigned short* __restrict__ Wp0, unsigned short* __restrict__ Wp1)
{
    const int t = blockIdx.x;
    const int tid = threadIdx.x;
    unsigned short outv[16];
    unsigned short* dst;
    if (t < T0) {
        const int ic = ic0_of(t), jc = jc0_of(t);
        #pragma unroll
        for (int q = 0; q < 16; ++q) {
            int pos  = tid * 16 + q;
            int e    = pos & 7, lane = (pos >> 3) & 63;
            int kh   = (pos >> 9) & 1, sq = pos >> 10;
            int s    = sq * 32 + (lane & 31);
            int i    = ic * 4 + kh * 2 + (lane >> 5);
            int j    = jc * 8 + e;
            float v = 0.0f;                                   // i>j: folded into (j,i)
            if (i < j)       v = W0[((size_t)(i * 40 + j)) * 128 + s]
                               + W0[((size_t)(j * 40 + i)) * 128 + s];
            else if (i == j) v = W0[((size_t)(i * 40 + i)) * 128 + s];
            outv[q] = f2h(v);
        }
        dst = Wp0 + (size_t)t * 4096 + tid * 16;
    } else {
        const int tt = t - T0;
        if (tt == 80) {                                       // zero pad tile
            #pragma unroll
            for (int q = 0; q < 16; ++q) outv[q] = 0;
        } else {
            const int jc = tt / 10, ic = tt % 10;
            #pragma unroll
            for (int q = 0; q < 16; ++q) {
                int pos  = tid * 16 + q;
                int e    = pos & 7, lane = (pos >> 3) & 63;
                int kh   = (pos >> 9) & 1, sq = pos >> 10;
                int s    = sq * 32 + (lane & 31);
                int i    = ic * 4 + kh * 2 + (lane >> 5);
                int j    = jc * 8 + e;
                outv[q] = f2h(W1[((size_t)(i * 64 + j)) * 128 + s]);
            }
        }
        dst = Wp1 + (size_t)tt * 4096 + tid * 16;
    }
    *(uint4*)dst       = *(const uint4*)outv;
    *(uint4*)(dst + 8) = *(const uint4*)(outv + 8);
}

// One GEMM phase.  16 waves: rt = wv>>2 (64 rows = 2 row-tiles of 32),
// sq = wv&3 (32 cols).  Per tile: 2 bv ds_read_b128 + 4 MFMA 32x32x16
// (16 pk_mul A-frag builds).  3-tile periods, global_load_lds double
// buffer, one barrier per period.
template<int T, int PHASE>
__device__ __forceinline__ void gemm_phase(
    const unsigned short* __restrict__ Wp,   // [T][4096] fp16, global, read-order layout
    const unsigned short* __restrict__ Jl,   // LDS j-source (Xl or NH)
    int jstride,                             // row stride of Jl in elems
    const unsigned int xk[2][10],            // [kh][ic]: X[row0,i]|X[row1,i]<<16, i=ic*4+kh*2+hb
    unsigned short* Wb,                      // LDS W double buffer [2][WBUF]
    f32x16 acc[2], int tid)
{
    const int lane = tid & 63;
    const int wv = tid >> 6;                 // wave id 0..15
    const int rt = wv >> 2;                  // row-tile pair (64 rows)
    const int sq = wv & 3;                   // s-quarter (32 cols)
    const int c31 = lane & 31;

    const unsigned short* jbase = Jl + (rt * 64 + c31) * jstride;

    // conflict-free bv base: addr = base + lane*16B (lane-linear)
    const unsigned short* brd = Wb + sq * 1024 + lane * 8;
    // DMA: 1024 thr x 16B = 2 tiles per call.  Call A: 16 waves, tiles
    // t0..t0+1; call B: waves 0..7, tile t0+2.  Identity layout.
    const unsigned short* gsrc = Wp + tid * 8;
    unsigned short* ldstA = Wb + wv * 512;
    unsigned short* ldstB = Wb + 8192 + wv * 512;

    auto stage_period = [&](int buf, int t0) {
        gl_lds16(gsrc + (size_t)t0 * 4096, ldstA + buf * WBUF);
        if (wv < 8)
            gl_lds16(gsrc + (size_t)(t0 + 2) * 4096, ldstB + buf * WBUF);
    };

    stage_period(0, 0);          // period 0 -> buf0
    __syncthreads();             // tiles landed

    uint4 jv0, jv1;              // j-octet for row-tile 0 / 1
    constexpr int NP = T / PERIOD;
    #pragma unroll
    for (int p = 0; p < NP; ++p) {
        const int cb = p & 1;                            // compute buffer
        const int nb = cb ^ 1;
        if ((p + 1) * PERIOD < T) stage_period(nb, (p + 1) * PERIOD);
        #pragma unroll
        for (int u = 0; u < PERIOD; ++u) {
            const int t  = p * PERIOD + u;               // compile-time
            const int ic = (PHASE == 0) ? ic0_of(t) : (t % 10);
            const int jc = (PHASE == 0) ? jc0_of(t) : (t / 10);
            const bool rl = (t == 0) ||
                (jc != ((PHASE == 0) ? jc0_of(t - 1) : ((t - 1) / 10)));
            if (rl) {                                    // jv reload (jc changed)
                jv0 = *(const uint4*)(jbase + jc * 8);
                jv1 = *(const uint4*)(jbase + 32 * jstride + jc * 8);
            }
            const unsigned short* bb_ = brd + cb * WBUF + u * 4096;
            #pragma unroll
            for (int kh = 0; kh < 2; ++kh) {             // K16 halves of the K32 tile
                uint4 bvv = *(const uint4*)(bb_ + kh * 512);
                half2v xp = __builtin_bit_cast(half2v, xk[kh][ic]);
                half2v x0 = {xp[0], xp[0]};              // row-tile 0 x-scalar
                half2v x1 = {xp[1], xp[1]};              // row-tile 1 x-scalar
                acc[0] = __builtin_amdgcn_mfma_f32_32x32x16_f16(
                    __builtin_bit_cast(half8, avmul(x0, jv0)),
                    __builtin_bit_cast(half8, bvv), acc[0], 0, 0, 0);
                acc[1] = __builtin_amdgcn_mfma_f32_32x32x16_f16(
                    __builtin_bit_cast(half8, avmul(x1, jv1)),
                    __builtin_bit_cast(half8, bvv), acc[1], 0, 0, 0);
            }
        }
        __syncthreads();     // nb DMA landed; cb reads done
    }
}

__global__ __launch_bounds__(1024, 4)
void fused_two_layer(const float* __restrict__ x,
                     const unsigned short* __restrict__ W0p,
                     const float* __restrict__ b0,
                     const unsigned short* __restrict__ W1p,
                     const float* __restrict__ b1,
                     float* __restrict__ out)
{
    __shared__ __align__(16) unsigned short Xl[256 * 40];   // 20.0 KB
    __shared__ __align__(16) unsigned short NH[256 * 72];   // 36.9 KB (144B rows,
        // 16B-aligned; cols 64..71 zero pad for the jc=8 pad tile)
    __shared__ __align__(16) unsigned short Wb[2 * WBUF];   // 48.0 KB W dbuf
    // total 104.9 KB -> 1 block/CU, 16 waves = 4 waves/SIMD by construction

    const int tid  = threadIdx.x;
    const int lane = tid & 63;
    const int wv   = tid >> 6;
    const int rt   = wv >> 2;           // 64-row pair
    const int sq   = wv & 3;            // s-quarter (32 cols)
    const int c31  = lane & 31;
    const int hb   = lane >> 5;

    // ---- stage X: x[8b][i][d] fp32 -> Xl[(bl*32+d)*40 + i] fp16 (RNE) ----
    const float* xblk = x + (size_t)blockIdx.x * (8 * 40 * 32);
    #pragma unroll
    for (int k = 0; k < 10; ++k) {
        int f = 1024 * k + tid;         // 0..10239, coalesced
        int bl = f / 1280, rem = f - bl * 1280;
        int i = rem >> 5, d = rem & 31;
        Xl[(bl * 32 + d) * 40 + i] = f2h(xblk[f]);
    }
    __syncthreads();

    // ---- preload this lane's i-scalars: i = ic*4 + kh*2 + hb, rows rt*64+c31
    //      (+32 for row-tile 1), packed lo/hi ----
    unsigned int xk[2][10];
    {
        const unsigned short* xr0 = Xl + (rt * 64 + c31) * 40;
        const unsigned short* xr1 = xr0 + 32 * 40;
        #pragma unroll
        for (int ic = 0; ic < 10; ++ic)
            #pragma unroll
            for (int kh = 0; kh < 2; ++kh) {
                unsigned int u0 = xr0[ic * 4 + kh * 2 + hb];
                unsigned int u1 = xr1[ic * 4 + kh * 2 + hb];
                xk[kh][ic] = u0 | (u1 << 16);
            }
    }

    f32x16 acc[2];
    #pragma unroll
    for (int rtt = 0; rtt < 2; ++rtt)
        #pragma unroll
        for (int rg = 0; rg < 16; ++rg) acc[rtt][rg] = 0.f;

    // ========== phase 0: 30 triangular tiles (Wsym), j from X ==========
    gemm_phase<T0, 0>(W0p, Xl, 40, xk, Wb, acc, tid);

    {   // epilogue 0: sq<2 (s<64) -> NH; sq>=2 -> d-sum -> out[:,0:64]
        float bs = b0[sq * 32 + c31];        // one bias scalar per lane
        if (sq < 2) {
            #pragma unroll
            for (int rtt = 0; rtt < 2; ++rtt)
                #pragma unroll
                for (int rg = 0; rg < 16; ++rg) {
                    int row = rt * 64 + rtt * 32 + (rg & 3) + 8 * (rg >> 2) + 4 * hb;
                    NH[row * 72 + sq * 32 + c31] =
                        f2h(fmaxf(acc[rtt][rg] + bs, 0.0f));
                }
        } else {
            #pragma unroll
            for (int rtt = 0; rtt < 2; ++rtt) {
                float s = 0.f;
                #pragma unroll
                for (int rg = 0; rg < 16; ++rg)
                    s += fmaxf(acc[rtt][rg] + bs, 0.0f);
                s += __shfl_xor(s, 32, 64);  // add other hb's 16 rows
                int bb = blockIdx.x * 8 + rt * 2 + rtt;   // 32-row tile == one batch
                if (lane < 32)
                    out[(size_t)bb * 192 + (sq - 2) * 32 + c31] = s;
            }
            if (sq == 2) {   // zero NH pad cols 64..71 (rows rt*64 + lane)
                int a = (rt * 64 + lane) * 72 + 64;       // byte 144r+128: 16B-aligned
                *(uint4*)&NH[a] = (uint4){0u, 0u, 0u, 0u};
            }
        }
    }
    __syncthreads();   // NH (incl. pad zeros) visible to all waves

    #pragma unroll
    for (int rtt = 0; rtt < 2; ++rtt)
        #pragma unroll
        for (int rg = 0; rg < 16; ++rg) acc[rtt][rg] = 0.f;

    // ========== phase 1: 81 tiles (80 real + pad), j from NH ==========
    gemm_phase<T1P, 1>(W1p, NH, 72, xk, Wb, acc, tid);

    {   // epilogue 1: bias+relu; d-sum -> out[:, 64:192]
        float bs = b1[sq * 32 + c31];
        #pragma unroll
        for (int rtt = 0; rtt < 2; ++rtt) {
            float s = 0.f;
            #pragma unroll
            for (int rg = 0; rg < 16; ++rg)
                s += fmaxf(acc[rtt][rg] + bs, 0.0f);
            s += __shfl_xor(s, 32, 64);
            int bb = blockIdx.x * 8 + rt * 2 + rtt;
            if (lane < 32)
                out[(size_t)bb * 192 + 64 + sq * 32 + c31] = s;
        }
    }
}

extern "C" void kernel_launch(void* const* d_in, const int* in_sizes, int n_in,
                              void* d_out, int out_size, void* d_ws, size_t ws_size,
                              hipStream_t stream) {
    const float* x  = (const float*)d_in[0];   // [2048][40][32]
    const float* W0 = (const float*)d_in[1];   // [40][40][128]
    const float* b0 = (const float*)d_in[2];   // [128]
    const float* W1 = (const float*)d_in[3];   // [40][64][128]
    const float* b1 = (const float*)d_in[4];   // [128]
    float* out = (float*)d_out;                // [2048][192]

    unsigned short* W0p = (unsigned short*)d_ws;                          // T0*8192  = 245760 B
    unsigned short* W1p = (unsigned short*)((char*)d_ws + T0 * 4096 * 2); // T1P*8192 = 663552 B

    permute_w_both<<<T0 + T1P, 256, 0, stream>>>(W0, W1, W0p, W1p);
    fused_two_layer<<<256, 1024, 0, stream>>>(x, W0p, b0, W1p, b1, out);
}

// Round 7
// 119.962 us; speedup vs baseline: 1.0134x; 1.0134x over previous
//
#include <hip/hip_runtime.h>
#include <stdint.h>

// ---------------------------------------------------------------------------
// B=2048, F0=40, D=32, LAYER0=LAYER1=128.  Rows r=b*32+d (65536).
//   phase0: h0[r,s] = relu(sum_{i<40,j<40} X[r,i]X[r,j] W0[i,j,s] + b0[s])
//   phase1: d1[r,s] = relu(sum_{i<40,j<64} X[r,i]NH[r,j] W1[i,j,s] + b1[s])
//   out[b,0:64] = sum_d h0[:,64:128]; out[b,64:192] = sum_d d1
//
// Round-16: COUNTED-VMCNT PIPELINE (T3/T4) + SETPRIO (T5).
// r10-r15 invariant: every variant on the "stage -> __syncthreads() full
// drain -> compute" skeleton pins MfmaUtil at 42-48% regardless of
// occupancy/spill/bv-traffic fixes == the m233 2-phase stall (lockstep
// convoy + vmcnt(0) drain).  This round replaces the sync structure:
//   - PERIOD=2 tiles, TRIPLE-buffered Wb (3 x 16KB).  Every thread issues
//     exactly ONE global_load_lds per stage -> uniform vmcnt counting.
//     30 = 15x2, 80 = 40x2: no pad tile, no NH pad cols (removed).
//   - loop p: s_waitcnt vmcnt(1)  [stage p landed; stage p+1 IN FLIGHT]
//             s_barrier            [raw; no drain]
//             issue stage p+2 into buf (p+2)%3  [freed by this barrier]
//             compute tiles 2p,2p+1 from buf p%3
//     vmcnt never drains to 0 mid-loop (m218 mechanism); last period
//     vmcnt(0).  FIFO vmcnt => stage(p) complete when <=1 outstanding.
//   - sched_barrier(0) fences around asm waits/barrier (rule #18).
//   - s_setprio(1/0) around each tile's MFMA cluster (T5).
// Datapath = r15 verbatim (32x32x16, bv-lean, 64-arch-reg fit, identity
// DMA W layout [sq][kh][lane][oct], symmetrized-triangular W0).
// Phase seams keep full __syncthreads() (drains epilogue stores so the
// next phase's vmcnt counting starts at 0).
// ---------------------------------------------------------------------------

typedef __attribute__((ext_vector_type(8))) _Float16 half8;
typedef __attribute__((ext_vector_type(2))) _Float16 half2v;
typedef __attribute__((ext_vector_type(16))) float f32x16;

#define T0 30        // phase0 tiles after triangular drop
#define T1 80        // phase1 tiles (even: no pad needed at PERIOD=2)
#define WBUF 8192    // halfwords per Wb buffer (2 tiles x 4096)

// phase-0 triangular schedule: jc blocks of sizes 2,4,6,8,10 (starts 0,2,6,12,20)
__host__ __device__ constexpr int ic0_of(int t) {
    return (t < 2) ? t : (t < 6) ? (t - 2) : (t < 12) ? (t - 6)
         : (t < 20) ? (t - 12) : (t - 20);
}
__host__ __device__ constexpr int jc0_of(int t) {
    return (t < 2) ? 0 : (t < 6) ? 1 : (t < 12) ? 2 : (t < 20) ? 3 : 4;
}

__device__ __forceinline__ unsigned short f2h(float f) {   // v_cvt_f16_f32, RNE
    return __builtin_bit_cast(unsigned short, (_Float16)f);
}
// async global->LDS DMA, 16 B/lane.  lds dest = (wave-uniform base) + lane*16.
__device__ __forceinline__ void gl_lds16(const unsigned short* g, unsigned short* l) {
    __builtin_amdgcn_global_load_lds(
        (const __attribute__((address_space(1))) unsigned int*)g,
        (__attribute__((address_space(3))) unsigned int*)l,
        16, 0, 0);
}
// A-fragment: broadcast x-scalar (both halves of xs) times 8 packed j-values.
__device__ __forceinline__ uint4 avmul(half2v xs, uint4 jv) {
    uint4 r;
    r.x = __builtin_bit_cast(unsigned int, (half2v)(xs * __builtin_bit_cast(half2v, jv.x)));
    r.y = __builtin_bit_cast(unsigned int, (half2v)(xs * __builtin_bit_cast(half2v, jv.y)));
    r.z = __builtin_bit_cast(unsigned int, (half2v)(xs * __builtin_bit_cast(half2v, jv.z)));
    r.w = __builtin_bit_cast(unsigned int, (half2v)(xs * __builtin_bit_cast(half2v, jv.w)));
    return r;
}

// ---------------------------------------------------------------------------
// Permute W -> Wp[t][ pos = sq*1024 + kh*512 + lane*8 + e ]:
//   s = sq*32 + (lane&31), hb = lane>>5, k = kh*16 + hb*8 + e,
//   i = ic*4 + kh*2 + hb, j = jc*8 + e.
// Exactly the 32x32x16 B-fragment read order (16B/lane, lane-linear) ->
// conflict-free ds_read_b128 AND identity global_load_lds staging.
// Phase0: symmetrized triangular Wsym.  110 blocks x 256 threads.
// ---------------------------------------------------------------------------
__global__ void permute_w_both(const float* __restrict__ W0, const float* __restrict__ W1,
                               unsigned short* __restrict__ Wp0, unsigned short* __restrict__ Wp1)
{
    const int t = blockIdx.x;
    const int tid = threadIdx.x;
    unsigned short outv[16];
    unsigned short* dst;
    if (t < T0) {
        const int ic = ic0_of(t), jc = jc0_of(t);
        #pragma unroll
        for (int q = 0; q < 16; ++q) {
            int pos  = tid * 16 + q;
            int e    = pos & 7, lane = (pos >> 3) & 63;
            int kh   = (pos >> 9) & 1, sq = pos >> 10;
            int s    = sq * 32 + (lane & 31);
            int i    = ic * 4 + kh * 2 + (lane >> 5);
            int j    = jc * 8 + e;
            float v = 0.0f;                                   // i>j: folded into (j,i)
            if (i < j)       v = W0[((size_t)(i * 40 + j)) * 128 + s]
                               + W0[((size_t)(j * 40 + i)) * 128 + s];
            else if (i == j) v = W0[((size_t)(i * 40 + i)) * 128 + s];
            outv[q] = f2h(v);
        }
        dst = Wp0 + (size_t)t * 4096 + tid * 16;
    } else {
        const int tt = t - T0;
        const int jc = tt / 10, ic = tt % 10;
        #pragma unroll
        for (int q = 0; q < 16; ++q) {
            int pos  = tid * 16 + q;
            int e    = pos & 7, lane = (pos >> 3) & 63;
            int kh   = (pos >> 9) & 1, sq = pos >> 10;
            int s    = sq * 32 + (lane & 31);
            int i    = ic * 4 + kh * 2 + (lane >> 5);
            int j    = jc * 8 + e;
            outv[q] = f2h(W1[((size_t)(i * 64 + j)) * 128 + s]);
        }
        dst = Wp1 + (size_t)tt * 4096 + tid * 16;
    }
    *(uint4*)dst       = *(const uint4*)outv;
    *(uint4*)(dst + 8) = *(const uint4*)(outv + 8);
}

// One GEMM phase, counted-vmcnt pipelined.  16 waves: rt = wv>>2 (64 rows),
// sq = wv&3 (32 cols).  Per tile: 2 bv ds_read_b128 + 4 MFMA 32x32x16.
// PERIOD=2 tiles; Wb triple-buffered; one raw barrier per period; vmcnt(1)
// steady state (never 0 mid-loop); stage p+2 issued post-barrier.
template<int T, int PHASE>
__device__ __forceinline__ void gemm_phase(
    const unsigned short* __restrict__ Wp,   // [T][4096] fp16, global, read-order layout
    const unsigned short* __restrict__ Jl,   // LDS j-source (Xl or NH)
    int jstride,                             // row stride of Jl in elems
    const unsigned int xk[2][10],            // [kh][ic]: X[row0,i]|X[row1,i]<<16, i=ic*4+kh*2+hb
    unsigned short* Wb,                      // LDS W TRIPLE buffer [3][WBUF]
    f32x16 acc[2], int tid)
{
    const int lane = tid & 63;
    const int wv = tid >> 6;                 // wave id 0..15
    const int rt = wv >> 2;                  // row-tile pair (64 rows)
    const int sq = wv & 3;                   // s-quarter (32 cols)
    const int c31 = lane & 31;

    const unsigned short* jbase = Jl + (rt * 64 + c31) * jstride;

    // conflict-free bv base: addr = base + lane*16B (lane-linear)
    const unsigned short* brd = Wb + sq * 1024 + lane * 8;
    // DMA: 1024 thr x 16B = 16KB = exactly one 2-tile stage per call.
    // Identity layout: per-thread src/dst offset tid*8 halfwords.
    const unsigned short* gsrc = Wp + tid * 8;
    unsigned short* ldst = Wb + tid * 8;

    auto stage = [&](int k) {   // stage period k (tiles 2k,2k+1) -> buf k%3
        gl_lds16(gsrc + (size_t)k * WBUF, ldst + (k % 3) * WBUF);
    };

    constexpr int NP = T / 2;
    stage(0);
    stage(1);

    uint4 jv0, jv1;              // j-octet for row-tile 0 / 1
    #pragma unroll
    for (int p = 0; p < NP; ++p) {
        // stage(p) landed?  FIFO vmcnt: <=1 outstanding => only stage(p+1)
        // may remain in flight.  Last period: everything must land.
        if (p == NP - 1) asm volatile("s_waitcnt vmcnt(0)" ::: "memory");
        else             asm volatile("s_waitcnt vmcnt(1)" ::: "memory");
        __builtin_amdgcn_sched_barrier(0);
        __builtin_amdgcn_s_barrier();        // raw: no vmcnt(0) drain
        __builtin_amdgcn_sched_barrier(0);
        if (p + 2 < NP) stage(p + 2);        // into buf freed by this barrier
        __builtin_amdgcn_sched_barrier(0);

        const unsigned short* bper = brd + (p % 3) * WBUF;
        #pragma unroll
        for (int u = 0; u < 2; ++u) {
            const int t  = p * 2 + u;                    // compile-time
            const int ic = (PHASE == 0) ? ic0_of(t) : (t % 10);
            const int jc = (PHASE == 0) ? jc0_of(t) : (t / 10);
            const bool rl = (t == 0) ||
                (jc != ((PHASE == 0) ? jc0_of(t - 1) : ((t - 1) / 10)));
            if (rl) {                                    // jv reload (jc changed)
                jv0 = *(const uint4*)(jbase + jc * 8);
                jv1 = *(const uint4*)(jbase + 32 * jstride + jc * 8);
            }
            __builtin_amdgcn_s_setprio(1);               // T5: favor MFMA cluster
            #pragma unroll
            for (int kh = 0; kh < 2; ++kh) {             // K16 halves of the K32 tile
                uint4 bvv = *(const uint4*)(bper + u * 4096 + kh * 512);
                half2v xp = __builtin_bit_cast(half2v, xk[kh][ic]);
                half2v x0 = {xp[0], xp[0]};              // row-tile 0 x-scalar
                half2v x1 = {xp[1], xp[1]};              // row-tile 1 x-scalar
                acc[0] = __builtin_amdgcn_mfma_f32_32x32x16_f16(
                    __builtin_bit_cast(half8, avmul(x0, jv0)),
                    __builtin_bit_cast(half8, bvv), acc[0], 0, 0, 0);
                acc[1] = __builtin_amdgcn_mfma_f32_32x32x16_f16(
                    __builtin_bit_cast(half8, avmul(x1, jv1)),
                    __builtin_bit_cast(half8, bvv), acc[1], 0, 0, 0);
            }
            __builtin_amdgcn_s_setprio(0);
        }
    }
    // loop exit: all DMAs drained (last period waited vmcnt(0)); no trailing
    // barrier here -- callers place a full __syncthreads() at phase seams.
}

__global__ __launch_bounds__(1024, 4)
void fused_two_layer(const float* __restrict__ x,
                     const unsigned short* __restrict__ W0p,
                     const float* __restrict__ b0,
                     const unsigned short* __restrict__ W1p,
                     const float* __restrict__ b1,
                     float* __restrict__ out)
{
    __shared__ __align__(16) unsigned short Xl[256 * 40];   // 20.0 KB
    __shared__ __align__(16) unsigned short NH[256 * 72];   // 36.9 KB (144B rows)
    __shared__ __align__(16) unsigned short Wb[3 * WBUF];   // 48.0 KB W triple buf
    // total 104.9 KB -> 1 block/CU, 16 waves = 4 waves/SIMD by construction

    const int tid  = threadIdx.x;
    const int lane = tid & 63;
    const int wv   = tid >> 6;
    const int rt   = wv >> 2;           // 64-row pair
    const int sq   = wv & 3;            // s-quarter (32 cols)
    const int c31  = lane & 31;
    const int hb   = lane >> 5;

    // ---- stage X: x[8b][i][d] fp32 -> Xl[(bl*32+d)*40 + i] fp16 (RNE) ----
    const float* xblk = x + (size_t)blockIdx.x * (8 * 40 * 32);
    #pragma unroll
    for (int k = 0; k < 10; ++k) {
        int f = 1024 * k + tid;         // 0..10239, coalesced
        int bl = f / 1280, rem = f - bl * 1280;
        int i = rem >> 5, d = rem & 31;
        Xl[(bl * 32 + d) * 40 + i] = f2h(xblk[f]);
    }
    __syncthreads();

    // ---- preload this lane's i-scalars: i = ic*4 + kh*2 + hb, rows rt*64+c31
    //      (+32 for row-tile 1), packed lo/hi ----
    unsigned int xk[2][10];
    {
        const unsigned short* xr0 = Xl + (rt * 64 + c31) * 40;
        const unsigned short* xr1 = xr0 + 32 * 40;
        #pragma unroll
        for (int ic = 0; ic < 10; ++ic)
            #pragma unroll
            for (int kh = 0; kh < 2; ++kh) {
                unsigned int u0 = xr0[ic * 4 + kh * 2 + hb];
                unsigned int u1 = xr1[ic * 4 + kh * 2 + hb];
                xk[kh][ic] = u0 | (u1 << 16);
            }
    }

    f32x16 acc[2];
    #pragma unroll
    for (int rtt = 0; rtt < 2; ++rtt)
        #pragma unroll
        for (int rg = 0; rg < 16; ++rg) acc[rtt][rg] = 0.f;

    // ========== phase 0: 30 triangular tiles (Wsym), j from X ==========
    gemm_phase<T0, 0>(W0p, Xl, 40, xk, Wb, acc, tid);

    {   // epilogue 0: sq<2 (s<64) -> NH; sq>=2 -> d-sum -> out[:,0:64]
        float bs = b0[sq * 32 + c31];        // one bias scalar per lane
        if (sq < 2) {
            #pragma unroll
            for (int rtt = 0; rtt < 2; ++rtt)
                #pragma unroll
                for (int rg = 0; rg < 16; ++rg) {
                    int row = rt * 64 + rtt * 32 + (rg & 3) + 8 * (rg >> 2) + 4 * hb;
                    NH[row * 72 + sq * 32 + c31] =
                        f2h(fmaxf(acc[rtt][rg] + bs, 0.0f));
                }
        } else {
            #pragma unroll
            for (int rtt = 0; rtt < 2; ++rtt) {
                float s = 0.f;
                #pragma unroll
                for (int rg = 0; rg < 16; ++rg)
                    s += fmaxf(acc[rtt][rg] + bs, 0.0f);
                s += __shfl_xor(s, 32, 64);  // add other hb's 16 rows
                int bb = blockIdx.x * 8 + rt * 2 + rtt;   // 32-row tile == one batch
                if (lane < 32)
                    out[(size_t)bb * 192 + (sq - 2) * 32 + c31] = s;
            }
        }
    }
    __syncthreads();   // NH visible to all; drains epilogue stores (vmcnt=0
                       // at phase-1 entry so its counted waits start clean)

    #pragma unroll
    for (int rtt = 0; rtt < 2; ++rtt)
        #pragma unroll
        for (int rg = 0; rg < 16; ++rg) acc[rtt][rg] = 0.f;

    // ========== phase 1: 80 tiles, j from NH ==========
    gemm_phase<T1, 1>(W1p, NH, 72, xk, Wb, acc, tid);

    {   // epilogue 1: bias+relu; d-sum -> out[:, 64:192]
        float bs = b1[sq * 32 + c31];
        #pragma unroll
        for (int rtt = 0; rtt < 2; ++rtt) {
            float s = 0.f;
            #pragma unroll
            for (int rg = 0; rg < 16; ++rg)
                s += fmaxf(acc[rtt][rg] + bs, 0.0f);
            s += __shfl_xor(s, 32, 64);
            int bb = blockIdx.x * 8 + rt * 2 + rtt;
            if (lane < 32)
                out[(size_t)bb * 192 + 64 + sq * 32 + c31] = s;
        }
    }
}

extern "C" void kernel_launch(void* const* d_in, const int* in_sizes, int n_in,
                              void* d_out, int out_size, void* d_ws, size_t ws_size,
                              hipStream_t stream) {
    const float* x  = (const float*)d_in[0];   // [2048][40][32]
    const float* W0 = (const float*)d_in[1];   // [40][40][128]
    const float* b0 = (const float*)d_in[2];   // [128]
    const float* W1 = (const float*)d_in[3];   // [40][64][128]
    const float* b1 = (const float*)d_in[4];   // [128]
    float* out = (float*)d_out;                // [2048][192]

    unsigned short* W0p = (unsigned short*)d_ws;                          // T0*8192 = 245760 B
    unsigned short* W1p = (unsigned short*)((char*)d_ws + T0 * 4096 * 2); // T1*8192 = 655360 B

    permute_w_both<<<T0 + T1, 256, 0, stream>>>(W0, W1, W0p, W1p);
    fused_two_layer<<<256, 1024, 0, stream>>>(x, W0p, b0, W1p, b1, out);
}

// Round 8
// 117.877 us; speedup vs baseline: 1.0313x; 1.0177x over previous
//
#include <hip/hip_runtime.h>
#include <stdint.h>

// ---------------------------------------------------------------------------
// B=2048, F0=40, D=32, LAYER0=LAYER1=128.  Rows r=b*32+d (65536).
//   phase0: h0[r,s] = relu(sum_{i<40,j<40} X[r,i]X[r,j] W0[i,j,s] + b0[s])
//   phase1: d1[r,s] = relu(sum_{i<40,j<64} X[r,i]NH[r,j] W1[i,j,s] + b1[s])
//   out[b,0:64] = sum_d h0[:,64:128]; out[b,64:192] = sum_d d1
//
// Round-17: INTRA-WAVE SOFTWARE PIPELINE.  r16 (counted vmcnt + setprio) was
// +3%: the barrier drain was never the stall (staged buffers always had a
// full period of slack).  The real signature: MfmaUtil 43 + VALUBusy 34 +
// idle 23 = pipes strictly SERIAL per wave ([avmul burst] -> [MFMA burst]
// dependency chain) and all 4 waves/SIMD in lockstep -> nobody has MFMA
// ready while anybody runs VALU.  Fix: rotate operands ahead of use:
//   - bvp[3]: bv ds_read issued 2 half-tiles ahead (~128 cyc of MFMA issue
//     covers ~120 cyc LDS latency);
//   - avp[2][2]: A-frag pair built 1 half-tile ahead; jv reloaded ahead on
//     jc change;
//   - body per half-tile h: [2 MFMA(h)] [ds_read bv(h+2)] [avmul av(h+1)]
//     -- slot WAR deps structurally pin the pipeline depth;
//   - period wait vmcnt(1)->vmcnt(0) (drained stage issued a full period
//     earlier => free) which makes CROSS-PERIOD prefetch legal: after
//     period p's barrier, buffers p%3 AND (p+1)%3 are landed+visible
//     (each wave waited vmcnt(0) for its own stage p+1 loads, then
//     barriered) -> no pipeline bubble at period seams.
// All rotation indices compile-time (full unroll; rule #20).  Registers:
// acc32 + xk20 + bvp12 + avp16 + jv8 + addr ~18 = ~106 <= 128: no spill.
// Carried from r16: PERIOD=2 triple-buffer Wb, raw s_barrier + counted
// vmcnt, setprio around MFMA pair, 32x32x16 datapath, identity-DMA W layout
// [sq][kh][lane][oct], symmetrized-triangular W0 (30 tiles), 1024-thr
// block (16 waves = 4 rt x 4 sq), phase-seam __syncthreads().
// ---------------------------------------------------------------------------

typedef __attribute__((ext_vector_type(8))) _Float16 half8;
typedef __attribute__((ext_vector_type(2))) _Float16 half2v;
typedef __attribute__((ext_vector_type(16))) float f32x16;

#define T0 30        // phase0 tiles after triangular drop
#define T1 80        // phase1 tiles
#define WBUF 8192    // halfwords per Wb buffer (2 tiles x 4096)

// phase-0 triangular schedule: jc blocks of sizes 2,4,6,8,10 (starts 0,2,6,12,20)
__host__ __device__ constexpr int ic0_of(int t) {
    return (t < 2) ? t : (t < 6) ? (t - 2) : (t < 12) ? (t - 6)
         : (t < 20) ? (t - 12) : (t - 20);
}
__host__ __device__ constexpr int jc0_of(int t) {
    return (t < 0) ? 0 : (t < 2) ? 0 : (t < 6) ? 1 : (t < 12) ? 2 : (t < 20) ? 3 : 4;
}

__device__ __forceinline__ unsigned short f2h(float f) {   // v_cvt_f16_f32, RNE
    return __builtin_bit_cast(unsigned short, (_Float16)f);
}
// async global->LDS DMA, 16 B/lane.  lds dest = (wave-uniform base) + lane*16.
__device__ __forceinline__ void gl_lds16(const unsigned short* g, unsigned short* l) {
    __builtin_amdgcn_global_load_lds(
        (const __attribute__((address_space(1))) unsigned int*)g,
        (__attribute__((address_space(3))) unsigned int*)l,
        16, 0, 0);
}
// A-fragment: broadcast x-scalar (both halves of xs) times 8 packed j-values.
__device__ __forceinline__ uint4 avmul(half2v xs, uint4 jv) {
    uint4 r;
    r.x = __builtin_bit_cast(unsigned int, (half2v)(xs * __builtin_bit_cast(half2v, jv.x)));
    r.y = __builtin_bit_cast(unsigned int, (half2v)(xs * __builtin_bit_cast(half2v, jv.y)));
    r.z = __builtin_bit_cast(unsigned int, (half2v)(xs * __builtin_bit_cast(half2v, jv.z)));
    r.w = __builtin_bit_cast(unsigned int, (half2v)(xs * __builtin_bit_cast(half2v, jv.w)));
    return r;
}

// ---------------------------------------------------------------------------
// Permute W -> Wp[t][ pos = sq*1024 + kh*512 + lane*8 + e ]:
//   s = sq*32 + (lane&31), hb = lane>>5, k = kh*16 + hb*8 + e,
//   i = ic*4 + kh*2 + hb, j = jc*8 + e.
// Exactly the 32x32x16 B-fragment read order (16B/lane, lane-linear) ->
// conflict-free ds_read_b128 AND identity global_load_lds staging.
// Phase0: symmetrized triangular Wsym.  110 blocks x 256 threads.
// ---------------------------------------------------------------------------
__global__ void permute_w_both(const float* __restrict__ W0, const float* __restrict__ W1,
                               unsigned short* __restrict__ Wp0, unsigned short* __restrict__ Wp1)
{
    const int t = blockIdx.x;
    const int tid = threadIdx.x;
    unsigned short outv[16];
    unsigned short* dst;
    if (t < T0) {
        const int ic = ic0_of(t), jc = jc0_of(t);
        #pragma unroll
        for (int q = 0; q < 16; ++q) {
            int pos  = tid * 16 + q;
            int e    = pos & 7, lane = (pos >> 3) & 63;
            int kh   = (pos >> 9) & 1, sq = pos >> 10;
            int s    = sq * 32 + (lane & 31);
            int i    = ic * 4 + kh * 2 + (lane >> 5);
            int j    = jc * 8 + e;
            float v = 0.0f;                                   // i>j: folded into (j,i)
            if (i < j)       v = W0[((size_t)(i * 40 + j)) * 128 + s]
                               + W0[((size_t)(j * 40 + i)) * 128 + s];
            else if (i == j) v = W0[((size_t)(i * 40 + i)) * 128 + s];
            outv[q] = f2h(v);
        }
        dst = Wp0 + (size_t)t * 4096 + tid * 16;
    } else {
        const int tt = t - T0;
        const int jc = tt / 10, ic = tt % 10;
        #pragma unroll
        for (int q = 0; q < 16; ++q) {
            int pos  = tid * 16 + q;
            int e    = pos & 7, lane = (pos >> 3) & 63;
            int kh   = (pos >> 9) & 1, sq = pos >> 10;
            int s    = sq * 32 + (lane & 31);
            int i    = ic * 4 + kh * 2 + (lane >> 5);
            int j    = jc * 8 + e;
            outv[q] = f2h(W1[((size_t)(i * 64 + j)) * 128 + s]);
        }
        dst = Wp1 + (size_t)tt * 4096 + tid * 16;
    }
    *(uint4*)dst       = *(const uint4*)outv;
    *(uint4*)(dst + 8) = *(const uint4*)(outv + 8);
}

// One GEMM phase, intra-wave software-pipelined + counted-vmcnt periods.
// 16 waves: rt = wv>>2 (64 rows), sq = wv&3 (32 cols).  Half-tile h =
// (tile t = h>>1, K16-half kh = h&1): 1 bv ds_read_b128 + 2 MFMA 32x32x16.
template<int T, int PHASE>
__device__ __forceinline__ void gemm_phase(
    const unsigned short* __restrict__ Wp,   // [T][4096] fp16, global, read-order layout
    const unsigned short* __restrict__ Jl,   // LDS j-source (Xl or NH)
    int jstride,                             // row stride of Jl in elems
    const unsigned int xk[2][10],            // [kh][ic]: X[row0,i]|X[row1,i]<<16, i=ic*4+kh*2+hb
    unsigned short* Wb,                      // LDS W TRIPLE buffer [3][WBUF]
    f32x16 acc[2], int tid)
{
    const int lane = tid & 63;
    const int wv = tid >> 6;                 // wave id 0..15
    const int rt = wv >> 2;                  // row-tile pair (64 rows)
    const int sq = wv & 3;                   // s-quarter (32 cols)
    const int c31 = lane & 31;

    const unsigned short* jbase0 = Jl + (rt * 64 + c31) * jstride;
    const unsigned short* jbase1 = jbase0 + 32 * jstride;
    const unsigned short* brd = Wb + sq * 1024 + lane * 8;   // lane-linear, 0-conflict
    const unsigned short* gsrc = Wp + tid * 8;
    unsigned short* ldst = Wb + tid * 8;

    constexpr int NP  = T / 2;               // 2-tile periods
    constexpr int NHT = T * 2;               // half-tiles

    // ---- stage periods 0,1; wait BOTH; barrier; stage 2 ----
    gl_lds16(gsrc, ldst);
    gl_lds16(gsrc + (size_t)WBUF, ldst + WBUF);
    asm volatile("s_waitcnt vmcnt(0)" ::: "memory");
    __builtin_amdgcn_sched_barrier(0);
    __builtin_amdgcn_s_barrier();            // bufs 0 AND 1 landed + visible
    __builtin_amdgcn_sched_barrier(0);
    gl_lds16(gsrc + (size_t)2 * WBUF, ldst + 2 * WBUF);

    // ---- pipeline prologue: jv(tile0), bv(h=0,1), av(h=0) ----
    uint4 jv0, jv1;
    {
        const int jc0 = (PHASE == 0) ? jc0_of(0) : 0;
        jv0 = *(const uint4*)(jbase0 + jc0 * 8);
        jv1 = *(const uint4*)(jbase1 + jc0 * 8);
    }
    uint4 bvp[3];                            // rotating bv slots (h%3)
    bvp[0] = *(const uint4*)(brd + 0 * 512); // h=0: buf0,u0,kh0
    bvp[1] = *(const uint4*)(brd + 1 * 512); // h=1: buf0,u0,kh1
    uint4 avp[2][2];                         // rotating av pairs (h%2)
    {
        const int ic0 = (PHASE == 0) ? ic0_of(0) : 0;
        half2v xp = __builtin_bit_cast(half2v, xk[0][ic0]);
        half2v x0 = {xp[0], xp[0]}, x1 = {xp[1], xp[1]};
        avp[0][0] = avmul(x0, jv0);
        avp[0][1] = avmul(x1, jv1);
    }

    #pragma unroll
    for (int p = 0; p < NP; ++p) {
        if (p > 0) {
            // own stage(p+1) loads landed (issued a full period ago -> ~free);
            // barrier makes ALL waves' stages <= p+1 visible -> cross-period
            // prefetch into buf (p+1)%3 during this period is safe.
            asm volatile("s_waitcnt vmcnt(0)" ::: "memory");
            __builtin_amdgcn_sched_barrier(0);
            __builtin_amdgcn_s_barrier();
            __builtin_amdgcn_sched_barrier(0);
            if (p + 2 < NP)
                gl_lds16(gsrc + (size_t)(p + 2) * WBUF, ldst + ((p + 2) % 3) * WBUF);
        }
        #pragma unroll
        for (int u2 = 0; u2 < 4; ++u2) {
            const int h = p * 4 + u2;        // compile-time half-tile index
            // ---- compute: 2 MFMA on h (operands already in regs) ----
            __builtin_amdgcn_s_setprio(1);
            acc[0] = __builtin_amdgcn_mfma_f32_32x32x16_f16(
                __builtin_bit_cast(half8, avp[h & 1][0]),
                __builtin_bit_cast(half8, bvp[h % 3]), acc[0], 0, 0, 0);
            acc[1] = __builtin_amdgcn_mfma_f32_32x32x16_f16(
                __builtin_bit_cast(half8, avp[h & 1][1]),
                __builtin_bit_cast(half8, bvp[h % 3]), acc[1], 0, 0, 0);
            __builtin_amdgcn_s_setprio(0);
            // ---- prefetch bv for h+2 (2-deep; may cross into buf (p+1)%3) ----
            if (h + 2 < NHT) {
                const int t2 = (h + 2) >> 1, kh2 = (h + 2) & 1;
                const int p2 = t2 >> 1,     u2b = t2 & 1;
                bvp[(h + 2) % 3] = *(const uint4*)
                    (brd + (p2 % 3) * WBUF + u2b * 4096 + kh2 * 512);
            }
            // ---- prefetch av (and jv on jc change) for h+1 (1-deep) ----
            if (h + 1 < NHT) {
                const int t1 = (h + 1) >> 1, kh1 = (h + 1) & 1;
                const int icn = (PHASE == 0) ? ic0_of(t1) : (t1 % 10);
                const int jcn = (PHASE == 0) ? jc0_of(t1) : (t1 / 10);
                const int jcp = (PHASE == 0) ? jc0_of(t1 - 1) : ((t1 - 1) / 10);
                if (kh1 == 0 && jcn != jcp) {
                    jv0 = *(const uint4*)(jbase0 + jcn * 8);
                    jv1 = *(const uint4*)(jbase1 + jcn * 8);
                }
                half2v xp = __builtin_bit_cast(half2v, xk[kh1][icn]);
                half2v x0 = {xp[0], xp[0]}, x1 = {xp[1], xp[1]};
                avp[(h + 1) & 1][0] = avmul(x0, jv0);
                avp[(h + 1) & 1][1] = avmul(x1, jv1);
            }
        }
    }
    // loop exit: all DMAs drained by the vmcnt(0) at period NP-2's top (last
    // stage issued at NP-3); callers place __syncthreads() at phase seams.
}

__global__ __launch_bounds__(1024, 4)
void fused_two_layer(const float* __restrict__ x,
                     const unsigned short* __restrict__ W0p,
                     const float* __restrict__ b0,
                     const unsigned short* __restrict__ W1p,
                     const float* __restrict__ b1,
                     float* __restrict__ out)
{
    __shared__ __align__(16) unsigned short Xl[256 * 40];   // 20.0 KB
    __shared__ __align__(16) unsigned short NH[256 * 72];   // 36.9 KB (144B rows)
    __shared__ __align__(16) unsigned short Wb[3 * WBUF];   // 48.0 KB W triple buf
    // total 104.9 KB -> 1 block/CU, 16 waves = 4 waves/SIMD by construction

    const int tid  = threadIdx.x;
    const int lane = tid & 63;
    const int wv   = tid >> 6;
    const int rt   = wv >> 2;           // 64-row pair
    const int sq   = wv & 3;            // s-quarter (32 cols)
    const int c31  = lane & 31;
    const int hb   = lane >> 5;

    // ---- stage X: x[8b][i][d] fp32 -> Xl[(bl*32+d)*40 + i] fp16 (RNE) ----
    const float* xblk = x + (size_t)blockIdx.x * (8 * 40 * 32);
    #pragma unroll
    for (int k = 0; k < 10; ++k) {
        int f = 1024 * k + tid;         // 0..10239, coalesced
        int bl = f / 1280, rem = f - bl * 1280;
        int i = rem >> 5, d = rem & 31;
        Xl[(bl * 32 + d) * 40 + i] = f2h(xblk[f]);
    }
    __syncthreads();

    // ---- preload this lane's i-scalars: i = ic*4 + kh*2 + hb, rows rt*64+c31
    //      (+32 for row-tile 1), packed lo/hi ----
    unsigned int xk[2][10];
    {
        const unsigned short* xr0 = Xl + (rt * 64 + c31) * 40;
        const unsigned short* xr1 = xr0 + 32 * 40;
        #pragma unroll
        for (int ic = 0; ic < 10; ++ic)
            #pragma unroll
            for (int kh = 0; kh < 2; ++kh) {
                unsigned int u0 = xr0[ic * 4 + kh * 2 + hb];
                unsigned int u1 = xr1[ic * 4 + kh * 2 + hb];
                xk[kh][ic] = u0 | (u1 << 16);
            }
    }

    f32x16 acc[2];
    #pragma unroll
    for (int rtt = 0; rtt < 2; ++rtt)
        #pragma unroll
        for (int rg = 0; rg < 16; ++rg) acc[rtt][rg] = 0.f;

    // ========== phase 0: 30 triangular tiles (Wsym), j from X ==========
    gemm_phase<T0, 0>(W0p, Xl, 40, xk, Wb, acc, tid);

    {   // epilogue 0: sq<2 (s<64) -> NH; sq>=2 -> d-sum -> out[:,0:64]
        float bs = b0[sq * 32 + c31];        // one bias scalar per lane
        if (sq < 2) {
            #pragma unroll
            for (int rtt = 0; rtt < 2; ++rtt)
                #pragma unroll
                for (int rg = 0; rg < 16; ++rg) {
                    int row = rt * 64 + rtt * 32 + (rg & 3) + 8 * (rg >> 2) + 4 * hb;
                    NH[row * 72 + sq * 32 + c31] =
                        f2h(fmaxf(acc[rtt][rg] + bs, 0.0f));
                }
        } else {
            #pragma unroll
            for (int rtt = 0; rtt < 2; ++rtt) {
                float s = 0.f;
                #pragma unroll
                for (int rg = 0; rg < 16; ++rg)
                    s += fmaxf(acc[rtt][rg] + bs, 0.0f);
                s += __shfl_xor(s, 32, 64);  // add other hb's 16 rows
                int bb = blockIdx.x * 8 + rt * 2 + rtt;   // 32-row tile == one batch
                if (lane < 32)
                    out[(size_t)bb * 192 + (sq - 2) * 32 + c31] = s;
            }
        }
    }
    __syncthreads();   // NH visible to all; drains vmcnt so phase-1 counting
                       // starts clean

    #pragma unroll
    for (int rtt = 0; rtt < 2; ++rtt)
        #pragma unroll
        for (int rg = 0; rg < 16; ++rg) acc[rtt][rg] = 0.f;

    // ========== phase 1: 80 tiles, j from NH ==========
    gemm_phase<T1, 1>(W1p, NH, 72, xk, Wb, acc, tid);

    {   // epilogue 1: bias+relu; d-sum -> out[:, 64:192]
        float bs = b1[sq * 32 + c31];
        #pragma unroll
        for (int rtt = 0; rtt < 2; ++rtt) {
            float s = 0.f;
            #pragma unroll
            for (int rg = 0; rg < 16; ++rg)
                s += fmaxf(acc[rtt][rg] + bs, 0.0f);
            s += __shfl_xor(s, 32, 64);
            int bb = blockIdx.x * 8 + rt * 2 + rtt;
            if (lane < 32)
                out[(size_t)bb * 192 + 64 + sq * 32 + c31] = s;
        }
    }
}

extern "C" void kernel_launch(void* const* d_in, const int* in_sizes, int n_in,
                              void* d_out, int out_size, void* d_ws, size_t ws_size,
                              hipStream_t stream) {
    const float* x  = (const float*)d_in[0];   // [2048][40][32]
    const float* W0 = (const float*)d_in[1];   // [40][40][128]
    const float* b0 = (const float*)d_in[2];   // [128]
    const float* W1 = (const float*)d_in[3];   // [40][64][128]
    const float* b1 = (const float*)d_in[4];   // [128]
    float* out = (float*)d_out;                // [2048][192]

    unsigned short* W0p = (unsigned short*)d_ws;                          // T0*8192 = 245760 B
    unsigned short* W1p = (unsigned short*)((char*)d_ws + T0 * 4096 * 2); // T1*8192 = 655360 B

    permute_w_both<<<T0 + T1, 256, 0, stream>>>(W0, W1, W0p, W1p);
    fused_two_layer<<<256, 1024, 0, stream>>>(x, W0p, b0, W1p, b1, out);
}